// Round 16
// baseline (472.413 us; speedup 1.0000x reference)
//
#include <hip/hip_runtime.h>
#include <hip/hip_bf16.h>

#define NN 50000
#define NE 800000
#define NG 50
#define NSL 16    // pool slices per graph
#define NSCB 196  // scan blocks (196*256 = 50176 >= NN+1)

typedef unsigned short u16;
typedef unsigned int u32;
typedef __attribute__((ext_vector_type(8))) short short8;
typedef __attribute__((ext_vector_type(4))) float float4v;
typedef __attribute__((ext_vector_type(2))) float f32x2;

__device__ __forceinline__ float b2f(u16 u) {
    union { u32 i; float f; } v; v.i = ((u32)u) << 16; return v.f;
}
__device__ __forceinline__ u16 f2b(float f) {
    union { float f; u32 i; } v; v.f = f;
    u32 i = v.i;
    return (u16)((i + 0x7FFFu + ((i >> 16) & 1u)) >> 16);
}
__device__ __forceinline__ float lo16f(u32 u) { union { u32 i; float f; } v; v.i = u << 16; return v.f; }
__device__ __forceinline__ float hi16f(u32 u) { union { u32 i; float f; } v; v.i = u & 0xffff0000u; return v.f; }

// ---------------- init + detect fused: zero cnt, init bounds; last block detects int64 ----------------
__global__ void k_init(const int* __restrict__ ei_raw, int* flag,
                       int* cnt, int* startg, int* endg) {
    __shared__ int cs[256];
    int i = blockIdx.x * blockDim.x + threadIdx.x;
    if (i < NN) cnt[i] = 0;
    if (i < NG) { startg[i] = 0x7fffffff; endg[i] = 0; }
    if (blockIdx.x == NSCB - 1) {
        int t = threadIdx.x;
        cs[t] = (ei_raw[2 * t + 1] == 0) ? 1 : 0;
        __syncthreads();
        for (int d = 128; d > 0; d >>= 1) {
            if (t < d) cs[t] += cs[t + d];
            __syncthreads();
        }
        if (t == 0) *flag = (cs[0] >= 128) ? 1 : 0;
    }
}

// ---------------- cvt: histogram dst + rank (u16) + batch32; NO bulk copies ----------------
__global__ void k_cvt(const int* __restrict__ ei_raw, const int* __restrict__ batch_raw,
                      const int* __restrict__ flag, int* __restrict__ batch32,
                      int* cnt, u16* __restrict__ rank) {
    int i = blockIdx.x * blockDim.x + threadIdx.x;
    int w = *flag;
    if (i < NE) {
        int d = w ? ei_raw[2 * (NE + i)] : ei_raw[NE + i];
        rank[i] = (u16)atomicAdd(&cnt[d], 1);   // rank within dst bucket
    }
    if (i < NN) batch32[i] = w ? batch_raw[2 * i] : batch_raw[i];
}

// ---------------- scan stage A: block-local exclusive scan + block sums ----------------
__global__ __launch_bounds__(256) void k_scanA(const int* __restrict__ cnt, int* __restrict__ excl,
                                               int* __restrict__ bsum) {
    __shared__ int s[256];
    int t = threadIdx.x, b = blockIdx.x;
    int i = b * 256 + t;
    int v = (i < NN) ? cnt[i] : 0;
    s[t] = v; __syncthreads();
    for (int d = 1; d < 256; d <<= 1) {
        int x = s[t];
        int y = (t >= d) ? s[t - d] : 0;
        __syncthreads();
        s[t] = x + y;
        __syncthreads();
    }
    excl[i] = s[t] - v;               // exclusive prefix within block
    if (t == 255) bsum[b] = s[255];   // block total
}

// ---------------- scan stage B: exclusive scan of block sums ----------------
__global__ __launch_bounds__(256) void k_scanB(const int* __restrict__ bsum, int* __restrict__ ebsum) {
    __shared__ int s[256];
    int t = threadIdx.x;
    int v = (t < NSCB) ? bsum[t] : 0;
    s[t] = v; __syncthreads();
    for (int d = 1; d < 256; d <<= 1) {
        int x = s[t];
        int y = (t >= d) ? s[t - d] : 0;
        __syncthreads();
        s[t] = x + y;
        __syncthreads();
    }
    ebsum[t] = s[t] - v;
}

// ---------------- scan stage C: combine ----------------
__global__ void k_scanC(const int* __restrict__ excl, const int* __restrict__ ebsum,
                        int* __restrict__ off) {
    int i = blockIdx.x * blockDim.x + threadIdx.x;
    if (i <= NN) off[i] = excl[i] + ebsum[i >> 8];
}

// ---------------- scatter: atomic-free, dst read from ei_raw, slot = off[dst] + rank ----------------
__global__ void k_scatter(const int* __restrict__ ei_raw, const int* __restrict__ flag,
                          const int* __restrict__ off, const u16* __restrict__ rank,
                          int* __restrict__ eid) {
    int e = blockIdx.x * blockDim.x + threadIdx.x;
    if (e >= NE) return;
    int w = *flag;
    int d = w ? ei_raw[2 * (NE + e)] : ei_raw[NE + e];
    eid[off[d] + (int)rank[e]] = e;
}

// ---------------- gw pack: gather src/attr from raw inputs via eid; write asrc + agw ----------------
struct GwParams { const float* mu[4]; const float* sg[4]; };
__global__ __launch_bounds__(256) void k_gwpack(const int* __restrict__ eid,
                                                const int* __restrict__ ei_raw,
                                                const float2* __restrict__ eattr2,
                                                const int* __restrict__ flag, GwParams P,
                                                u32* __restrict__ asrc, uint2* __restrict__ agw) {
    int j = blockIdx.x * blockDim.x + threadIdx.x;
    if (j >= NE) return;
    int e = eid[j];
    int w = *flag;
    int s = w ? ei_raw[2 * e] : ei_raw[e];
    float2 at = eattr2[e];
    float a0 = at.x, a1 = at.y;
    asrc[j] = (u32)s;
#pragma unroll
    for (int l = 0; l < 4; l++) {
        u16 wq[4];
#pragma unroll
        for (int k = 0; k < 4; k++) {
            float d0 = a0 - P.mu[l][2 * k], d1 = a1 - P.mu[l][2 * k + 1];
            float s0 = P.sg[l][2 * k], s1 = P.sg[l][2 * k + 1];
            float t = d0 * d0 / (1e-15f + s0 * s0) + d1 * d1 / (1e-15f + s1 * s1);
            wq[k] = f2b(expf(-0.5f * t));
        }
        uint2 o;
        o.x = (u32)wq[0] | ((u32)wq[1] << 16);
        o.y = (u32)wq[2] | ((u32)wq[3] << 16);
        agw[(size_t)l * NE + j] = o;
    }
}

// ---------------- prep fused: x->bf16 | weight swizzle | graph bounds ----------------
struct WParams { const float* g[4]; const float* rw[4]; };
__global__ void k_prep(const float* __restrict__ x, u16* __restrict__ xb,
                       WParams P, u16* __restrict__ bsw,
                       const int* __restrict__ batch, int* startg, int* endg) {
    int b = blockIdx.x, t = threadIdx.x;
    if (b < 12500) {                       // x2b: NN*64 = 3.2M elements
        int i = b * 256 + t;
        if (i < NN * 64) xb[i] = f2b(x[i]);
    } else if (b < 12820) {                // wprep: 4*20480 = 81920 ids
        int id = (b - 12500) * 256 + t;
        if (id < 4 * 20480) {
            int l = id / 20480, r = id % 20480;
            int j = r & 7, lane = (r >> 3) & 63, ctkt = r >> 9;
            int ct = ctkt & 3, kt = ctkt >> 2;
            int k = kt * 32 + (lane >> 4) * 8 + j;
            int n = ct * 16 + (lane & 15);
            float v;
            if (k < 256) v = P.g[l][(k & 63) * 256 + (k >> 6) * 64 + n];
            else         v = P.rw[l][(k - 256) * 64 + n];
            bsw[id] = f2b(v);
        }
    } else {                               // bounds: NN boundary scan
        int n = (b - 12820) * 256 + t;
        if (n >= NN) return;
        int bb = batch[n];
        if (n == 0) {
            startg[bb] = 0;
        } else {
            int bp = batch[n - 1];
            if (bp != bb) { startg[bb] = n; endg[bp] = n; }
        }
        if (n == NN - 1) endg[bb] = NN;
    }
}

// ---------------- aggregation: y[n][k*64+d] = (1/deg) sum_e gw[e][k]*x[src][d] ----------------
// one wave per node; 4 edge-groups x 16 lanes; lane covers 4 features (8B loads); pk-fma
__global__ __launch_bounds__(256) void k_agg(const u16* __restrict__ xin,
                                             const u32* __restrict__ asrc,
                                             const uint2* __restrict__ agw,
                                             const int* __restrict__ off,
                                             u16* __restrict__ y) {
    int wid = (blockIdx.x * 256 + threadIdx.x) >> 6;  // node, one wave each
    int lane = threadIdx.x & 63;
    int g = lane >> 4;        // edge group 0..3
    int f = lane & 15;        // feature quad: features 4f..4f+3
    if (wid >= NN) return;
    int beg = off[wid], end = off[wid + 1];
    f32x2 acc[4][2];          // [k][pair]
#pragma unroll
    for (int k = 0; k < 4; k++) {
        acc[k][0] = (f32x2){0.f, 0.f};
        acc[k][1] = (f32x2){0.f, 0.f};
    }

    int niter = (end - beg + 3) >> 2;
#pragma unroll 2
    for (int it = 0; it < niter; it++) {
        int j = beg + it * 4 + g;
        u32 s = 0; uint2 wv = make_uint2(0, 0);     // tail: gw=0, src row 0 valid
        if (j < end) { s = asrc[j]; wv = agw[j]; }
        uint2 xr = *(const uint2*)(xin + (size_t)s * 64 + f * 4);
        f32x2 x01, x23;
        x01.x = lo16f(xr.x); x01.y = hi16f(xr.x);
        x23.x = lo16f(xr.y); x23.y = hi16f(xr.y);
        float w0 = lo16f(wv.x), w1 = hi16f(wv.x);
        float w2 = lo16f(wv.y), w3 = hi16f(wv.y);
        acc[0][0] += w0 * x01; acc[0][1] += w0 * x23;
        acc[1][0] += w1 * x01; acc[1][1] += w1 * x23;
        acc[2][0] += w2 * x01; acc[2][1] += w2 * x23;
        acc[3][0] += w3 * x01; acc[3][1] += w3 * x23;
    }

    // reduce across the 4 edge-groups (lanes differing in bits 4,5)
#pragma unroll
    for (int k = 0; k < 4; k++)
#pragma unroll
        for (int p = 0; p < 2; p++) {
            float v0 = acc[k][p].x, v1 = acc[k][p].y;
            v0 += __shfl_xor(v0, 16, 64); v0 += __shfl_xor(v0, 32, 64);
            v1 += __shfl_xor(v1, 16, 64); v1 += __shfl_xor(v1, 32, 64);
            acc[k][p].x = v0; acc[k][p].y = v1;
        }

    int deg = end - beg;
    float sc = 1.0f / (float)(deg > 1 ? deg : 1);
    u16 o0 = f2b(acc[g][0].x * sc), o1 = f2b(acc[g][0].y * sc);
    u16 o2 = f2b(acc[g][1].x * sc), o3 = f2b(acc[g][1].y * sc);
    uint2 pk;
    pk.x = (u32)o0 | ((u32)o1 << 16);
    pk.y = (u32)o2 | ((u32)o3 << 16);
    *(uint2*)(y + (size_t)wid * 256 + g * 64 + f * 4) = pk;
}

// ---------------- GEMM: xout = lrelu([y|xin](N,320) @ Wcat(320,64) + b); opt x3 = x0 + xout ----------------
#define LDA 328  // 320 + 8 u16 pad -> rows 656B, 16B aligned
__global__ __launch_bounds__(256) void k_gemm(const u16* __restrict__ y,
                                              const u16* __restrict__ xin,
                                              const u16* __restrict__ bsw,
                                              const float* __restrict__ bias,
                                              u16* __restrict__ xout,
                                              const u16* __restrict__ xadd,
                                              u16* __restrict__ x3out) {
    __shared__ u16 As[64 * LDA];
    int t = threadIdx.x;
    int rbase = blockIdx.x * 64;
#pragma unroll
    for (int c = 0; c < 10; c++) {
        int idx = t + c * 256;
        int row = idx / 40, pos = idx % 40;
        int grow = rbase + row;
        uint4 v = make_uint4(0, 0, 0, 0);
        if (grow < NN) {
            if (pos < 32) v = *(const uint4*)(y + (size_t)grow * 256 + pos * 8);
            else          v = *(const uint4*)(xin + (size_t)grow * 64 + (pos - 32) * 8);
        }
        *(uint4*)(&As[row * LDA + pos * 8]) = v;
    }
    __syncthreads();

    int wave = t >> 6, lane = t & 63, lr = lane & 15, lg = lane >> 4;
    float4v acc0 = {0.f,0.f,0.f,0.f}, acc1 = {0.f,0.f,0.f,0.f};
    float4v acc2 = {0.f,0.f,0.f,0.f}, acc3 = {0.f,0.f,0.f,0.f};
    const u16* ar = &As[(wave * 16 + lr) * LDA + lg * 8];
    const uint4* bp = (const uint4*)bsw;
    for (int kt = 0; kt < 10; kt++) {
        short8 a  = *(const short8*)(ar + kt * 32);
        short8 b0 = *(const short8*)(bp + (kt * 4 + 0) * 64 + lane);
        short8 b1 = *(const short8*)(bp + (kt * 4 + 1) * 64 + lane);
        short8 b2 = *(const short8*)(bp + (kt * 4 + 2) * 64 + lane);
        short8 b3 = *(const short8*)(bp + (kt * 4 + 3) * 64 + lane);
        acc0 = __builtin_amdgcn_mfma_f32_16x16x32_bf16(a, b0, acc0, 0, 0, 0);
        acc1 = __builtin_amdgcn_mfma_f32_16x16x32_bf16(a, b1, acc1, 0, 0, 0);
        acc2 = __builtin_amdgcn_mfma_f32_16x16x32_bf16(a, b2, acc2, 0, 0, 0);
        acc3 = __builtin_amdgcn_mfma_f32_16x16x32_bf16(a, b3, acc3, 0, 0, 0);
    }
    float4v accs[4] = {acc0, acc1, acc2, acc3};
#pragma unroll
    for (int ct = 0; ct < 4; ct++) {
        int col = ct * 16 + lr;
        float bv = bias[col];
#pragma unroll
        for (int reg = 0; reg < 4; reg++) {
            int grow = rbase + wave * 16 + lg * 4 + reg;  // C/D: row=(lane>>4)*4+reg, col=lane&15
            if (grow < NN) {
                float v = accs[ct][reg] + bv;
                v = v > 0.f ? v : 0.01f * v;
                xout[(size_t)grow * 64 + col] = f2b(v);
                if (x3out) {
                    float s2 = v + b2f(xadd[(size_t)grow * 64 + col]);
                    x3out[(size_t)grow * 64 + col] = f2b(s2);
                }
            }
        }
    }
}

// ---------------- pool stage 1: partial max over node slice, concat [x4,x1,x2,x3] ----------------
__global__ __launch_bounds__(256) void k_pool1(const u16* __restrict__ x4, const u16* __restrict__ x1,
                                               const u16* __restrict__ x2, const u16* __restrict__ x3,
                                               const int* __restrict__ startg, const int* __restrict__ endg,
                                               float* __restrict__ partial) {
    int g = blockIdx.x, sl = blockIdx.y;
    int c = threadIdx.x;
    const u16* arr = (c < 64) ? x4 : (c < 128) ? x1 : (c < 192) ? x2 : x3;
    int h = c & 63;
    int s = startg[g], e = endg[g];
    int len = e - s;
    int chunk = (len + NSL - 1) / NSL;
    int s0 = s + sl * chunk;
    int e0 = s0 + chunk; if (e0 > e) e0 = e;
    float m = -3.4e38f;
    for (int n = s0; n < e0; n++) {
        float v = b2f(arr[(size_t)n * 64 + h]);
        m = v > m ? v : m;
    }
    partial[((size_t)g * NSL + sl) * 256 + c] = m;
}

// ---------------- final MLP fused with pool stage 2 ----------------
__global__ void k_final(const float* __restrict__ partial, const float* __restrict__ w1,
                        const float* __restrict__ b1, const float* __restrict__ gamma,
                        const float* __restrict__ beta, const float* __restrict__ w2,
                        const float* __restrict__ b2v, float* __restrict__ out) {
    __shared__ float pld[256];
    __shared__ float zsh[64];
    int g = blockIdx.x, h = threadIdx.x;
    for (int c = h; c < 256; c += 64) {
        float m = -3.4e38f;
#pragma unroll
        for (int sl = 0; sl < NSL; sl++) {
            float v = partial[((size_t)g * NSL + sl) * 256 + c];
            m = v > m ? v : m;
        }
        pld[c] = m;
    }
    __syncthreads();
    float z = b1[h];
    for (int j = 0; j < 256; j++) z += pld[j] * w1[j * 64 + h];
    z = z * 0.9999950000374997f * gamma[h] + beta[h];  // /sqrt(1+1e-5)
    z = z > 0.f ? z : 0.f;
    zsh[h] = z;
    __syncthreads();
    if (h < 10) {
        float o = b2v[h];
        for (int k = 0; k < 64; k++) o += zsh[k] * w2[k * 10 + h];
        out[g * 10 + h] = o;   // fp32 output
    }
}

extern "C" void kernel_launch(void* const* d_in, const int* in_sizes, int n_in,
                              void* d_out, int out_size, void* d_ws, size_t ws_size,
                              hipStream_t stream) {
    const float* x_in    = (const float*)d_in[0];
    const int* ei_raw    = (const int*)d_in[1];
    const int* batch_raw = (const int*)d_in[2];
    const float* eattr   = (const float*)d_in[3];

    const float *g_[4], *mu_[4], *sg_[4], *rw_[4], *b_[4];
    for (int i = 0; i < 4; i++) {
        g_[i]  = (const float*)d_in[4 + 5 * i + 0];
        mu_[i] = (const float*)d_in[4 + 5 * i + 1];
        sg_[i] = (const float*)d_in[4 + 5 * i + 2];
        rw_[i] = (const float*)d_in[4 + 5 * i + 3];
        b_[i]  = (const float*)d_in[4 + 5 * i + 4];
    }
    const float* w_mlp1 = (const float*)d_in[24];
    const float* b_mlp1 = (const float*)d_in[25];
    const float* bn_g   = (const float*)d_in[26];
    const float* bn_b   = (const float*)d_in[27];
    const float* w_mlp2 = (const float*)d_in[28];
    const float* b_mlp2 = (const float*)d_in[29];
    float* out = (float*)d_out;

    // workspace carve-up (~50 MB)
    char* ws = (char*)d_ws;
    size_t o = 0;
    auto take = [&](size_t bytes) { size_t r = o; o += (bytes + 255) & ~(size_t)255; return r; };
    int*   flag     = (int*)(ws + take(4));
    u16*   rank     = (u16*)(ws + take((size_t)NE * 2));
    int*   batch32  = (int*)(ws + take((size_t)NN * 4));
    int*   off      = (int*)(ws + take((NN + 1) * 4));
    int*   cnt      = (int*)(ws + take((size_t)NN * 4));
    int*   excl     = (int*)(ws + take((size_t)NSCB * 256 * 4));
    int*   bsum     = (int*)(ws + take((size_t)NSCB * 4));
    int*   ebsum    = (int*)(ws + take(256 * 4));
    int*   eid      = (int*)(ws + take((size_t)NE * 4));
    u32*   asrc     = (u32*)(ws + take((size_t)NE * 4));
    uint2* agw      = (uint2*)(ws + take((size_t)4 * NE * 8));
    u16*   xb       = (u16*)(ws + take((size_t)NN * 64 * 2));
    u16*   y        = (u16*)(ws + take((size_t)NN * 256 * 2));
    u16*   x0       = (u16*)(ws + take((size_t)NN * 64 * 2));
    u16*   x1       = (u16*)(ws + take((size_t)NN * 64 * 2));
    u16*   x2       = (u16*)(ws + take((size_t)NN * 64 * 2));
    u16*   x3       = (u16*)(ws + take((size_t)NN * 64 * 2));
    u16*   x4       = (u16*)(ws + take((size_t)NN * 64 * 2));
    u16*   bsw      = (u16*)(ws + take((size_t)4 * 320 * 64 * 2));
    float* partial  = (float*)(ws + take((size_t)NG * NSL * 256 * 4));
    int*   startg   = (int*)(ws + take(NG * 4));
    int*   endg     = (int*)(ws + take(NG * 4));
    (void)ws_size; (void)in_sizes; (void)n_in; (void)out_size;

    k_init<<<dim3(NSCB), dim3(256), 0, stream>>>(ei_raw, flag, cnt, startg, endg);
    k_cvt<<<dim3((NE + 255) / 256), dim3(256), 0, stream>>>(
        ei_raw, batch_raw, flag, batch32, cnt, rank);

    k_scanA<<<dim3(NSCB), dim3(256), 0, stream>>>(cnt, excl, bsum);
    k_scanB<<<dim3(1), dim3(256), 0, stream>>>(bsum, ebsum);
    k_scanC<<<dim3(NSCB), dim3(256), 0, stream>>>(excl, ebsum, off);
    k_scatter<<<dim3(NE / 256), dim3(256), 0, stream>>>(ei_raw, flag, off, rank, eid);

    WParams WP;
    for (int i = 0; i < 4; i++) { WP.g[i] = g_[i]; WP.rw[i] = rw_[i]; }
    k_prep<<<dim3(13016), dim3(256), 0, stream>>>(x_in, xb, WP, bsw, batch32, startg, endg);

    GwParams GP;
    for (int i = 0; i < 4; i++) { GP.mu[i] = mu_[i]; GP.sg[i] = sg_[i]; }
    k_gwpack<<<dim3(NE / 256), dim3(256), 0, stream>>>(
        eid, ei_raw, (const float2*)eattr, flag, GP, asrc, agw);

    const int aggGrid = NN / 4;            // 4 waves (nodes) per 256-thr block
    const int gemmGrid = (NN + 63) / 64;   // 64 rows per block

    const u16* lin[4]  = {xb, x0, x1, x3};
    u16*       lout[4] = {x0, x1, x2, x4};
    for (int l = 0; l < 4; l++) {
        k_agg<<<dim3(aggGrid), dim3(256), 0, stream>>>(
            lin[l], asrc, agw + (size_t)l * NE, off, y);
        k_gemm<<<dim3(gemmGrid), dim3(256), 0, stream>>>(
            y, lin[l], bsw + (size_t)l * 20480, b_[l], lout[l],
            (l == 2) ? x0 : (const u16*)nullptr,
            (l == 2) ? x3 : (u16*)nullptr);
    }

    k_pool1<<<dim3(NG, NSL), dim3(256), 0, stream>>>(x4, x1, x2, x3, startg, endg, partial);
    k_final<<<dim3(NG), dim3(64), 0, stream>>>(partial, w_mlp1, b_mlp1, bn_g, bn_b, w_mlp2, b_mlp2, out);
}

// Round 17
// 459.413 us; speedup vs baseline: 1.0283x; 1.0283x over previous
//
#include <hip/hip_runtime.h>
#include <hip/hip_bf16.h>

#define NN 50000
#define NE 800000
#define NG 50
#define NSL 16    // pool slices per graph
#define NSCB 196  // scan blocks (196*256 = 50176 >= NN+1)

typedef unsigned short u16;
typedef unsigned int u32;
typedef __attribute__((ext_vector_type(8))) short short8;
typedef __attribute__((ext_vector_type(4))) float float4v;
typedef __attribute__((ext_vector_type(2))) float f32x2;

__device__ __forceinline__ float b2f(u16 u) {
    union { u32 i; float f; } v; v.i = ((u32)u) << 16; return v.f;
}
__device__ __forceinline__ u16 f2b(float f) {
    union { float f; u32 i; } v; v.f = f;
    u32 i = v.i;
    return (u16)((i + 0x7FFFu + ((i >> 16) & 1u)) >> 16);
}
__device__ __forceinline__ float lo16f(u32 u) { union { u32 i; float f; } v; v.i = u << 16; return v.f; }
__device__ __forceinline__ float hi16f(u32 u) { union { u32 i; float f; } v; v.i = u & 0xffff0000u; return v.f; }

// ---------------- init + detect + gaussian-coef precompute ----------------
struct SgP { const float* mu[4]; const float* sg[4]; };
__global__ void k_init(const int* __restrict__ ei_raw, int* flag,
                       int* cnt, int* startg, int* endg, SgP S, float* __restrict__ gcoef) {
    __shared__ int cs[256];
    int i = blockIdx.x * blockDim.x + threadIdx.x;
    if (i < NN) cnt[i] = 0;
    if (i < NG) { startg[i] = 0x7fffffff; endg[i] = 0; }
    if (blockIdx.x == 0 && threadIdx.x < 64) {
        int t = threadIdx.x;          // [l][k][d] coef then [l][k][d] mu
        int l = (t >> 3) & 3, kd = t & 7;
        if (t < 32) {
            float s = S.sg[l][kd];
            gcoef[t] = -0.5f / (1e-15f + s * s);
        } else {
            gcoef[t] = S.mu[l][kd];   // gcoef[32 + l*8 + kd]
        }
    }
    if (blockIdx.x == NSCB - 1) {
        int t = threadIdx.x;
        cs[t] = (ei_raw[2 * t + 1] == 0) ? 1 : 0;
        __syncthreads();
        for (int d = 128; d > 0; d >>= 1) {
            if (t < d) cs[t] += cs[t + d];
            __syncthreads();
        }
        if (t == 0) *flag = (cs[0] >= 128) ? 1 : 0;
    }
}

// ---------------- cvt + prep mega-fusion: rank-hist | x2b | wprep | bounds ----------------
struct WParams { const float* g[4]; const float* rw[4]; };
__global__ void k_cvtprep(const int* __restrict__ ei_raw, const int* __restrict__ batch_raw,
                          const int* __restrict__ flag, int* cnt, u16* __restrict__ rank,
                          const float* __restrict__ x, u16* __restrict__ xb,
                          WParams P, u16* __restrict__ bsw,
                          int* startg, int* endg) {
    int b = blockIdx.x, t = threadIdx.x;
    if (b < 3125) {                        // rank histogram: NE = 3125*256
        int e = b * 256 + t;
        int w = *flag;
        int d = w ? ei_raw[2 * (NE + e)] : ei_raw[NE + e];
        rank[e] = (u16)atomicAdd(&cnt[d], 1);
    } else if (b < 15625) {                // x2b: NN*64 = 3.2M
        int i = (b - 3125) * 256 + t;
        if (i < NN * 64) xb[i] = f2b(x[i]);
    } else if (b < 15945) {                // wprep: 4*20480 ids
        int id = (b - 15625) * 256 + t;
        if (id < 4 * 20480) {
            int l = id / 20480, r = id % 20480;
            int j = r & 7, lane = (r >> 3) & 63, ctkt = r >> 9;
            int ct = ctkt & 3, kt = ctkt >> 2;
            int k = kt * 32 + (lane >> 4) * 8 + j;
            int n = ct * 16 + (lane & 15);
            float v;
            if (k < 256) v = P.g[l][(k & 63) * 256 + (k >> 6) * 64 + n];
            else         v = P.rw[l][(k - 256) * 64 + n];
            bsw[id] = f2b(v);
        }
    } else {                               // bounds: boundary scan on raw batch
        int n = (b - 15945) * 256 + t;
        if (n >= NN) return;
        int w = *flag;
        int bb = w ? batch_raw[2 * n] : batch_raw[n];
        if (n == 0) {
            startg[bb] = 0;
        } else {
            int bp = w ? batch_raw[2 * (n - 1)] : batch_raw[n - 1];
            if (bp != bb) { startg[bb] = n; endg[bp] = n; }
        }
        if (n == NN - 1) endg[bb] = NN;
    }
}

// ---------------- scan stage A: block-local exclusive scan + block sums ----------------
__global__ __launch_bounds__(256) void k_scanA(const int* __restrict__ cnt, int* __restrict__ excl,
                                               int* __restrict__ bsum) {
    __shared__ int s[256];
    int t = threadIdx.x, b = blockIdx.x;
    int i = b * 256 + t;
    int v = (i < NN) ? cnt[i] : 0;
    s[t] = v; __syncthreads();
    for (int d = 1; d < 256; d <<= 1) {
        int x = s[t];
        int y = (t >= d) ? s[t - d] : 0;
        __syncthreads();
        s[t] = x + y;
        __syncthreads();
    }
    excl[i] = s[t] - v;               // exclusive prefix within block
    if (t == 255) bsum[b] = s[255];   // block total
}

// ---------------- scan stage B+C fused: every block re-scans bsum locally, writes off ----------------
__global__ __launch_bounds__(256) void k_scanBC(const int* __restrict__ excl,
                                                const int* __restrict__ bsum,
                                                int* __restrict__ off) {
    __shared__ int s[256];
    int t = threadIdx.x, b = blockIdx.x;
    int v = (t < NSCB) ? bsum[t] : 0;
    s[t] = v; __syncthreads();
    for (int d = 1; d < 256; d <<= 1) {
        int x = s[t];
        int y = (t >= d) ? s[t - d] : 0;
        __syncthreads();
        s[t] = x + y;
        __syncthreads();
    }
    int ebase = (b == 0) ? 0 : s[b - 1];
    int i = b * 256 + t;
    if (i <= NN) off[i] = excl[i] + ebase;
}

// ---------------- scatter: atomic-free, dst read from ei_raw, slot = off[dst] + rank ----------------
__global__ void k_scatter(const int* __restrict__ ei_raw, const int* __restrict__ flag,
                          const int* __restrict__ off, const u16* __restrict__ rank,
                          int* __restrict__ eid) {
    int e = blockIdx.x * blockDim.x + threadIdx.x;
    if (e >= NE) return;
    int w = *flag;
    int d = w ? ei_raw[2 * (NE + e)] : ei_raw[NE + e];
    eid[off[d] + (int)rank[e]] = e;
}

// ---------------- gw pack: precomputed coefs, __expf; write asrc + agw ----------------
__global__ __launch_bounds__(256) void k_gwpack(const int* __restrict__ eid,
                                                const int* __restrict__ ei_raw,
                                                const float2* __restrict__ eattr2,
                                                const int* __restrict__ flag,
                                                const float* __restrict__ gcoef,
                                                u32* __restrict__ asrc, uint2* __restrict__ agw) {
    int j = blockIdx.x * blockDim.x + threadIdx.x;
    if (j >= NE) return;
    int e = eid[j];
    int w = *flag;
    int s = w ? ei_raw[2 * e] : ei_raw[e];
    float2 at = eattr2[e];
    float a0 = at.x, a1 = at.y;
    asrc[j] = (u32)s;
#pragma unroll
    for (int l = 0; l < 4; l++) {
        u16 wq[4];
#pragma unroll
        for (int k = 0; k < 4; k++) {
            float m0 = gcoef[32 + l * 8 + 2 * k], m1 = gcoef[32 + l * 8 + 2 * k + 1];
            float c0 = gcoef[l * 8 + 2 * k],      c1 = gcoef[l * 8 + 2 * k + 1];
            float d0 = a0 - m0, d1 = a1 - m1;
            float t = d0 * d0 * c0 + d1 * d1 * c1;   // t <= 0, c includes -0.5
            wq[k] = f2b(__expf(t));
        }
        uint2 o;
        o.x = (u32)wq[0] | ((u32)wq[1] << 16);
        o.y = (u32)wq[2] | ((u32)wq[3] << 16);
        agw[(size_t)l * NE + j] = o;
    }
}

// ---------------- aggregation: y[n][k*64+d] = (1/deg) sum_e gw[e][k]*x[src][d] ----------------
__global__ __launch_bounds__(256) void k_agg(const u16* __restrict__ xin,
                                             const u32* __restrict__ asrc,
                                             const uint2* __restrict__ agw,
                                             const int* __restrict__ off,
                                             u16* __restrict__ y) {
    int wid = (blockIdx.x * 256 + threadIdx.x) >> 6;  // node, one wave each
    int lane = threadIdx.x & 63;
    int g = lane >> 4;        // edge group 0..3
    int f = lane & 15;        // feature quad: features 4f..4f+3
    if (wid >= NN) return;
    int beg = off[wid], end = off[wid + 1];
    f32x2 acc[4][2];          // [k][pair]
#pragma unroll
    for (int k = 0; k < 4; k++) {
        acc[k][0] = (f32x2){0.f, 0.f};
        acc[k][1] = (f32x2){0.f, 0.f};
    }

    int niter = (end - beg + 3) >> 2;
#pragma unroll 2
    for (int it = 0; it < niter; it++) {
        int j = beg + it * 4 + g;
        u32 s = 0; uint2 wv = make_uint2(0, 0);     // tail: gw=0, src row 0 valid
        if (j < end) { s = asrc[j]; wv = agw[j]; }
        uint2 xr = *(const uint2*)(xin + (size_t)s * 64 + f * 4);
        f32x2 x01, x23;
        x01.x = lo16f(xr.x); x01.y = hi16f(xr.x);
        x23.x = lo16f(xr.y); x23.y = hi16f(xr.y);
        float w0 = lo16f(wv.x), w1 = hi16f(wv.x);
        float w2 = lo16f(wv.y), w3 = hi16f(wv.y);
        acc[0][0] += w0 * x01; acc[0][1] += w0 * x23;
        acc[1][0] += w1 * x01; acc[1][1] += w1 * x23;
        acc[2][0] += w2 * x01; acc[2][1] += w2 * x23;
        acc[3][0] += w3 * x01; acc[3][1] += w3 * x23;
    }

    // reduce across the 4 edge-groups (lanes differing in bits 4,5)
#pragma unroll
    for (int k = 0; k < 4; k++)
#pragma unroll
        for (int p = 0; p < 2; p++) {
            float v0 = acc[k][p].x, v1 = acc[k][p].y;
            v0 += __shfl_xor(v0, 16, 64); v0 += __shfl_xor(v0, 32, 64);
            v1 += __shfl_xor(v1, 16, 64); v1 += __shfl_xor(v1, 32, 64);
            acc[k][p].x = v0; acc[k][p].y = v1;
        }

    int deg = end - beg;
    float sc = 1.0f / (float)(deg > 1 ? deg : 1);
    u16 o0 = f2b(acc[g][0].x * sc), o1 = f2b(acc[g][0].y * sc);
    u16 o2 = f2b(acc[g][1].x * sc), o3 = f2b(acc[g][1].y * sc);
    uint2 pk;
    pk.x = (u32)o0 | ((u32)o1 << 16);
    pk.y = (u32)o2 | ((u32)o3 << 16);
    *(uint2*)(y + (size_t)wid * 256 + g * 64 + f * 4) = pk;
}

// ---------------- GEMM: xout = lrelu([y|xin](N,320) @ Wcat(320,64) + b); opt x3 = x0 + xout ----------------
#define LDA 328  // 320 + 8 u16 pad -> rows 656B, 16B aligned
__global__ __launch_bounds__(256) void k_gemm(const u16* __restrict__ y,
                                              const u16* __restrict__ xin,
                                              const u16* __restrict__ bsw,
                                              const float* __restrict__ bias,
                                              u16* __restrict__ xout,
                                              const u16* __restrict__ xadd,
                                              u16* __restrict__ x3out) {
    __shared__ u16 As[64 * LDA];
    int t = threadIdx.x;
    int rbase = blockIdx.x * 64;
#pragma unroll
    for (int c = 0; c < 10; c++) {
        int idx = t + c * 256;
        int row = idx / 40, pos = idx % 40;
        int grow = rbase + row;
        uint4 v = make_uint4(0, 0, 0, 0);
        if (grow < NN) {
            if (pos < 32) v = *(const uint4*)(y + (size_t)grow * 256 + pos * 8);
            else          v = *(const uint4*)(xin + (size_t)grow * 64 + (pos - 32) * 8);
        }
        *(uint4*)(&As[row * LDA + pos * 8]) = v;
    }
    __syncthreads();

    int wave = t >> 6, lane = t & 63, lr = lane & 15, lg = lane >> 4;
    float4v acc0 = {0.f,0.f,0.f,0.f}, acc1 = {0.f,0.f,0.f,0.f};
    float4v acc2 = {0.f,0.f,0.f,0.f}, acc3 = {0.f,0.f,0.f,0.f};
    const u16* ar = &As[(wave * 16 + lr) * LDA + lg * 8];
    const uint4* bp = (const uint4*)bsw;
    for (int kt = 0; kt < 10; kt++) {
        short8 a  = *(const short8*)(ar + kt * 32);
        short8 b0 = *(const short8*)(bp + (kt * 4 + 0) * 64 + lane);
        short8 b1 = *(const short8*)(bp + (kt * 4 + 1) * 64 + lane);
        short8 b2 = *(const short8*)(bp + (kt * 4 + 2) * 64 + lane);
        short8 b3 = *(const short8*)(bp + (kt * 4 + 3) * 64 + lane);
        acc0 = __builtin_amdgcn_mfma_f32_16x16x32_bf16(a, b0, acc0, 0, 0, 0);
        acc1 = __builtin_amdgcn_mfma_f32_16x16x32_bf16(a, b1, acc1, 0, 0, 0);
        acc2 = __builtin_amdgcn_mfma_f32_16x16x32_bf16(a, b2, acc2, 0, 0, 0);
        acc3 = __builtin_amdgcn_mfma_f32_16x16x32_bf16(a, b3, acc3, 0, 0, 0);
    }
    float4v accs[4] = {acc0, acc1, acc2, acc3};
#pragma unroll
    for (int ct = 0; ct < 4; ct++) {
        int col = ct * 16 + lr;
        float bv = bias[col];
#pragma unroll
        for (int reg = 0; reg < 4; reg++) {
            int grow = rbase + wave * 16 + lg * 4 + reg;  // C/D: row=(lane>>4)*4+reg, col=lane&15
            if (grow < NN) {
                float v = accs[ct][reg] + bv;
                v = v > 0.f ? v : 0.01f * v;
                xout[(size_t)grow * 64 + col] = f2b(v);
                if (x3out) {
                    float s2 = v + b2f(xadd[(size_t)grow * 64 + col]);
                    x3out[(size_t)grow * 64 + col] = f2b(s2);
                }
            }
        }
    }
}

// ---------------- pool stage 1: partial max over node slice, concat [x4,x1,x2,x3] ----------------
__global__ __launch_bounds__(256) void k_pool1(const u16* __restrict__ x4, const u16* __restrict__ x1,
                                               const u16* __restrict__ x2, const u16* __restrict__ x3,
                                               const int* __restrict__ startg, const int* __restrict__ endg,
                                               float* __restrict__ partial) {
    int g = blockIdx.x, sl = blockIdx.y;
    int c = threadIdx.x;
    const u16* arr = (c < 64) ? x4 : (c < 128) ? x1 : (c < 192) ? x2 : x3;
    int h = c & 63;
    int s = startg[g], e = endg[g];
    int len = e - s;
    int chunk = (len + NSL - 1) / NSL;
    int s0 = s + sl * chunk;
    int e0 = s0 + chunk; if (e0 > e) e0 = e;
    float m = -3.4e38f;
    for (int n = s0; n < e0; n++) {
        float v = b2f(arr[(size_t)n * 64 + h]);
        m = v > m ? v : m;
    }
    partial[((size_t)g * NSL + sl) * 256 + c] = m;
}

// ---------------- final MLP fused with pool stage 2 ----------------
__global__ void k_final(const float* __restrict__ partial, const float* __restrict__ w1,
                        const float* __restrict__ b1, const float* __restrict__ gamma,
                        const float* __restrict__ beta, const float* __restrict__ w2,
                        const float* __restrict__ b2v, float* __restrict__ out) {
    __shared__ float pld[256];
    __shared__ float zsh[64];
    int g = blockIdx.x, h = threadIdx.x;
    for (int c = h; c < 256; c += 64) {
        float m = -3.4e38f;
#pragma unroll
        for (int sl = 0; sl < NSL; sl++) {
            float v = partial[((size_t)g * NSL + sl) * 256 + c];
            m = v > m ? v : m;
        }
        pld[c] = m;
    }
    __syncthreads();
    float z = b1[h];
    for (int j = 0; j < 256; j++) z += pld[j] * w1[j * 64 + h];
    z = z * 0.9999950000374997f * gamma[h] + beta[h];  // /sqrt(1+1e-5)
    z = z > 0.f ? z : 0.f;
    zsh[h] = z;
    __syncthreads();
    if (h < 10) {
        float o = b2v[h];
        for (int k = 0; k < 64; k++) o += zsh[k] * w2[k * 10 + h];
        out[g * 10 + h] = o;   // fp32 output
    }
}

extern "C" void kernel_launch(void* const* d_in, const int* in_sizes, int n_in,
                              void* d_out, int out_size, void* d_ws, size_t ws_size,
                              hipStream_t stream) {
    const float* x_in    = (const float*)d_in[0];
    const int* ei_raw    = (const int*)d_in[1];
    const int* batch_raw = (const int*)d_in[2];
    const float* eattr   = (const float*)d_in[3];

    const float *g_[4], *mu_[4], *sg_[4], *rw_[4], *b_[4];
    for (int i = 0; i < 4; i++) {
        g_[i]  = (const float*)d_in[4 + 5 * i + 0];
        mu_[i] = (const float*)d_in[4 + 5 * i + 1];
        sg_[i] = (const float*)d_in[4 + 5 * i + 2];
        rw_[i] = (const float*)d_in[4 + 5 * i + 3];
        b_[i]  = (const float*)d_in[4 + 5 * i + 4];
    }
    const float* w_mlp1 = (const float*)d_in[24];
    const float* b_mlp1 = (const float*)d_in[25];
    const float* bn_g   = (const float*)d_in[26];
    const float* bn_b   = (const float*)d_in[27];
    const float* w_mlp2 = (const float*)d_in[28];
    const float* b_mlp2 = (const float*)d_in[29];
    float* out = (float*)d_out;

    // workspace carve-up (~50 MB)
    char* ws = (char*)d_ws;
    size_t o = 0;
    auto take = [&](size_t bytes) { size_t r = o; o += (bytes + 255) & ~(size_t)255; return r; };
    int*   flag     = (int*)(ws + take(4));
    float* gcoef    = (float*)(ws + take(64 * 4));
    u16*   rank     = (u16*)(ws + take((size_t)NE * 2));
    int*   off      = (int*)(ws + take((NN + 1) * 4));
    int*   cnt      = (int*)(ws + take((size_t)NN * 4));
    int*   excl     = (int*)(ws + take((size_t)NSCB * 256 * 4));
    int*   bsum     = (int*)(ws + take((size_t)NSCB * 4));
    int*   eid      = (int*)(ws + take((size_t)NE * 4));
    u32*   asrc     = (u32*)(ws + take((size_t)NE * 4));
    uint2* agw      = (uint2*)(ws + take((size_t)4 * NE * 8));
    u16*   xb       = (u16*)(ws + take((size_t)NN * 64 * 2));
    u16*   y        = (u16*)(ws + take((size_t)NN * 256 * 2));
    u16*   x0       = (u16*)(ws + take((size_t)NN * 64 * 2));
    u16*   x1       = (u16*)(ws + take((size_t)NN * 64 * 2));
    u16*   x2       = (u16*)(ws + take((size_t)NN * 64 * 2));
    u16*   x3       = (u16*)(ws + take((size_t)NN * 64 * 2));
    u16*   x4       = (u16*)(ws + take((size_t)NN * 64 * 2));
    u16*   bsw      = (u16*)(ws + take((size_t)4 * 320 * 64 * 2));
    float* partial  = (float*)(ws + take((size_t)NG * NSL * 256 * 4));
    int*   startg   = (int*)(ws + take(NG * 4));
    int*   endg     = (int*)(ws + take(NG * 4));
    (void)ws_size; (void)in_sizes; (void)n_in; (void)out_size;

    SgP SP;
    for (int i = 0; i < 4; i++) { SP.mu[i] = mu_[i]; SP.sg[i] = sg_[i]; }
    k_init<<<dim3(NSCB), dim3(256), 0, stream>>>(ei_raw, flag, cnt, startg, endg, SP, gcoef);

    WParams WP;
    for (int i = 0; i < 4; i++) { WP.g[i] = g_[i]; WP.rw[i] = rw_[i]; }
    k_cvtprep<<<dim3(16141), dim3(256), 0, stream>>>(
        ei_raw, batch_raw, flag, cnt, rank, x_in, xb, WP, bsw, startg, endg);

    k_scanA<<<dim3(NSCB), dim3(256), 0, stream>>>(cnt, excl, bsum);
    k_scanBC<<<dim3(NSCB), dim3(256), 0, stream>>>(excl, bsum, off);
    k_scatter<<<dim3(NE / 256), dim3(256), 0, stream>>>(ei_raw, flag, off, rank, eid);

    k_gwpack<<<dim3(NE / 256), dim3(256), 0, stream>>>(
        eid, ei_raw, (const float2*)eattr, flag, gcoef, asrc, agw);

    const int aggGrid = NN / 4;            // 4 waves (nodes) per 256-thr block
    const int gemmGrid = (NN + 63) / 64;   // 64 rows per block

    const u16* lin[4]  = {xb, x0, x1, x3};
    u16*       lout[4] = {x0, x1, x2, x4};
    for (int l = 0; l < 4; l++) {
        k_agg<<<dim3(aggGrid), dim3(256), 0, stream>>>(
            lin[l], asrc, agw + (size_t)l * NE, off, y);
        k_gemm<<<dim3(gemmGrid), dim3(256), 0, stream>>>(
            y, lin[l], bsw + (size_t)l * 20480, b_[l], lout[l],
            (l == 2) ? x0 : (const u16*)nullptr,
            (l == 2) ? x3 : (u16*)nullptr);
    }

    k_pool1<<<dim3(NG, NSL), dim3(256), 0, stream>>>(x4, x1, x2, x3, startg, endg, partial);
    k_final<<<dim3(NG), dim3(64), 0, stream>>>(partial, w_mlp1, b_mlp1, bn_g, bn_b, w_mlp2, b_mlp2, out);
}